// Round 2
// baseline (564.108 us; speedup 1.0000x reference)
//
#include <hip/hip_runtime.h>

#define SINGLE_DIM 256
#define PAIR_DIM   64
#define MAX_REL    32
#define LN_EPS     1e-5f
#define N_FIXED    1024

typedef float vfloat4 __attribute__((ext_vector_type(4)));

// ---------------------------------------------------------------------------
// Kernel A (proven): proj[row][c], c in [0,128): c<64 -> s@W_i + bias, else s@W_j
// One block = 2 rows x 128 cols = 256 threads, one output element per thread.
// ---------------------------------------------------------------------------
__global__ __launch_bounds__(256) void proj_kernel(
    const float* __restrict__ s,     // (B*N, 256)
    const float* __restrict__ W,     // (512, 64) = [W_i; W_j]
    const float* __restrict__ bias,  // (64,)
    float* __restrict__ proj)        // (B*N, 128) = [pi+b | pj]
{
    __shared__ float lds[2][SINGLE_DIM];
    const int row0 = blockIdx.x * 2;
    const int t = threadIdx.x;

    ((float2*)(&lds[0][0]))[t] = ((const float2*)(s + (size_t)row0 * SINGLE_DIM))[t];
    __syncthreads();

    const int row  = t >> 7;         // 0..1 (wave-uniform)
    const int c    = t & 127;        // 0..127
    const int half = c >> 6;         // wave-uniform
    const int p    = c & 63;

    const float* wcol = W + half * (SINGLE_DIM * PAIR_DIM) + p;
    const float* srow = lds[row];

    float acc = (half == 0) ? bias[p] : 0.f;
    #pragma unroll 8
    for (int d = 0; d < SINGLE_DIM; ++d)
        acc += srow[d] * wcol[d * PAIR_DIM];

    proj[(size_t)(row0 + row) * 128 + c] = acc;
}

// ---------------------------------------------------------------------------
// Kernel B (fused): block = one bi x 64 consecutive j.
// Phase 1: LN stats per j via algebraic identity:
//   mean = (Si + Sj)/64,  E[x^2] = (Qi + Qj + 2<pi',pj>)/64.
//   4 threads per j, 16-channel partials, 2-round 4-lane shuffle reduce,
//   (mean, rstd) -> 512 B LDS.  10 DS ops/thread vs 32 in the old reduce,
//   and the output path has ZERO cross-lane dependencies.
// Phase 2: pure streaming epilogue (identical layout/coalescing to the
//   proven kernel: 16-lane group per bi x 4 j, stride-16 j for coalescing).
// Workspace: 1 MB proj only (proven size; no fallback needed).
// ---------------------------------------------------------------------------
__global__ __launch_bounds__(256) void pair_fused_kernel(
    const float* __restrict__ proj,   // (B*N, 128)
    const float* __restrict__ gamma,  // (64,)
    const float* __restrict__ beta,   // (64,)
    const float* __restrict__ embed,  // (65, 64)
    float* __restrict__ out)          // (B, N, N, 64)
{
    __shared__ float2 ms[64];         // (mean, rstd) per j in tile

    const int t   = threadIdx.x;
    const int bid = blockIdx.x;
    const int bi  = bid >> 4;                  // row index b*N + i
    const int j0  = (bid & 15) * 64;
    const int i   = bi & (N_FIXED - 1);
    const int b   = bi >> 10;
    const size_t jrow0 = (size_t)b * N_FIXED + j0;   // global proj row of first j

    // ---------------- phase 1: per-j stats ----------------
    {
        const int jl   = t >> 2;               // 0..63: local j
        const int part = t & 3;                // 16-channel slice
        const float* pip = proj + (size_t)bi * 128 + part * 16;
        const float* pjp = proj + (jrow0 + jl) * 128 + 64 + part * 16;

        float dot = 0.f, si = 0.f, qi = 0.f, sj = 0.f, qj = 0.f;
        #pragma unroll
        for (int c = 0; c < 4; ++c) {
            const float4 a  = *(const float4*)(pip + c * 4);
            const float4 bb = *(const float4*)(pjp + c * 4);
            dot += a.x * bb.x + a.y * bb.y + a.z * bb.z + a.w * bb.w;
            si  += a.x + a.y + a.z + a.w;
            qi  += a.x * a.x + a.y * a.y + a.z * a.z + a.w * a.w;
            sj  += bb.x + bb.y + bb.z + bb.w;
            qj  += bb.x * bb.x + bb.y * bb.y + bb.z * bb.z + bb.w * bb.w;
        }

        #pragma unroll
        for (int mask = 1; mask < 4; mask <<= 1) {
            dot += __shfl_xor(dot, mask, 64);
            si  += __shfl_xor(si,  mask, 64);
            qi  += __shfl_xor(qi,  mask, 64);
            sj  += __shfl_xor(sj,  mask, 64);
            qj  += __shfl_xor(qj,  mask, 64);
        }

        if (part == 0) {
            const float mean = (si + sj) * (1.f / PAIR_DIM);
            const float ex2  = (qi + qj + 2.f * dot) * (1.f / PAIR_DIM);
            const float rstd = rsqrtf(ex2 - mean * mean + LN_EPS);
            ms[jl] = make_float2(mean, rstd);
        }
    }

    // phase-2 per-thread constants (issue before the barrier)
    const int g  = t >> 4;                     // group 0..15
    const int p0 = (t & 15) * 4;
    const float4 pi4 = *(const float4*)(proj + (size_t)bi * 128 + p0);
    const float4 g4  = *(const float4*)(gamma + p0);
    const float4 b4  = *(const float4*)(beta + p0);

    __syncthreads();

    // ---------------- phase 2: streaming epilogue ----------------
    #pragma unroll
    for (int k = 0; k < 4; ++k) {
        const int jl = g + 16 * k;
        const int j  = j0 + jl;
        const float4 pj4 = *(const float4*)(proj + (jrow0 + jl) * 128 + 64 + p0);
        const float2 mr  = ms[jl];             // LDS broadcast across the group
        const float mean = mr.x, rstd = mr.y;

        const float Gx = g4.x * rstd, Gy = g4.y * rstd,
                    Gz = g4.z * rstd, Gw = g4.w * rstd;
        const float Bx = fmaf(-mean, Gx, b4.x), By = fmaf(-mean, Gy, b4.y),
                    Bz = fmaf(-mean, Gz, b4.z), Bw = fmaf(-mean, Gw, b4.w);

        int rel = j - i;
        rel = (rel < -MAX_REL) ? -MAX_REL : (rel > MAX_REL ? MAX_REL : rel);
        rel += MAX_REL;
        const float4 e4 = *(const float4*)(embed + rel * PAIR_DIM + p0);

        vfloat4 o;
        o.x = fmaxf(fmaf(pi4.x + pj4.x, Gx, Bx), 0.f) + e4.x;
        o.y = fmaxf(fmaf(pi4.y + pj4.y, Gy, By), 0.f) + e4.y;
        o.z = fmaxf(fmaf(pi4.z + pj4.z, Gz, Bz), 0.f) + e4.z;
        o.w = fmaxf(fmaf(pi4.w + pj4.w, Gw, Bw), 0.f) + e4.w;

        __builtin_nontemporal_store(o,
            (vfloat4*)(out + ((size_t)bi * N_FIXED + j) * PAIR_DIM + p0));
    }
}

extern "C" void kernel_launch(void* const* d_in, const int* in_sizes, int n_in,
                              void* d_out, int out_size, void* d_ws, size_t ws_size,
                              hipStream_t stream) {
    const float* s     = (const float*)d_in[0];   // (B, N, 256)
    const float* W     = (const float*)d_in[1];   // (512, 64)
    const float* bias  = (const float*)d_in[2];   // (64,)
    const float* gamma = (const float*)d_in[3];   // (64,)
    const float* beta  = (const float*)d_in[4];   // (64,)
    const float* embed = (const float*)d_in[5];   // (65, 64)
    float* out  = (float*)d_out;
    float* proj = (float*)d_ws;                   // (B*N, 128) = 1 MB (proven)

    const int BN = in_sizes[0] / SINGLE_DIM;      // B*N = 2048

    proj_kernel<<<BN / 2, 256, 0, stream>>>(s, W, bias, proj);

    const int blocks = BN * (N_FIXED / 64);       // 32768
    pair_fused_kernel<<<blocks, 256, 0, stream>>>(proj, gamma, beta, embed, out);
}

// Round 3
// 529.830 us; speedup vs baseline: 1.0647x; 1.0647x over previous
//
#include <hip/hip_runtime.h>

#define SINGLE_DIM 256
#define PAIR_DIM   64
#define MAX_REL    32
#define LN_EPS     1e-5f
#define N_FIXED    1024

typedef float vfloat4 __attribute__((ext_vector_type(4)));

// DPP row_ror sum over each 16-lane row: VALU pipe only, no DS ops.
// ctrl: 0x120 | N = row_ror:N (GFX9-lineage DPP, present on CDNA).
#define DPP_ADD(x, ctrl)                                                    \
    ((x) + __int_as_float(__builtin_amdgcn_update_dpp(                      \
               0, __float_as_int(x), (ctrl), 0xf, 0xf, true)))

__device__ __forceinline__ float rowsum16(float x) {
    x = DPP_ADD(x, 0x128);   // ror:8
    x = DPP_ADD(x, 0x124);   // ror:4
    x = DPP_ADD(x, 0x122);   // ror:2
    x = DPP_ADD(x, 0x121);   // ror:1
    return x;                // all 16 lanes hold the row sum
}

// ---------------------------------------------------------------------------
// Kernel A: proj[row][c], c in [0,128): c<64 -> s@W_i + bias, else s@W_j.
// Block = 2 rows x 128 cols = 256 threads. Each wave is uniform in
// (row, half) -> a full-wave reduce of (acc, acc^2) yields per-row-half
// stats (Si,Qi | Sj,Qj) for free (2048 waves total, ~1 us).
// ---------------------------------------------------------------------------
__global__ __launch_bounds__(256) void proj_kernel(
    const float* __restrict__ s,        // (B*N, 256)
    const float* __restrict__ W,        // (512, 64) = [W_i; W_j]
    const float* __restrict__ bias,     // (64,)
    float* __restrict__ proj,           // (B*N, 128) = [pi+b | pj]
    float* __restrict__ rowstats)       // (B*N, 4) = Si,Qi,Sj,Qj  (or null)
{
    __shared__ float lds[2][SINGLE_DIM];
    const int row0 = blockIdx.x * 2;
    const int t = threadIdx.x;

    ((float2*)(&lds[0][0]))[t] = ((const float2*)(s + (size_t)row0 * SINGLE_DIM))[t];
    __syncthreads();

    const int row  = t >> 7;         // 0..1 (wave-uniform)
    const int c    = t & 127;        // 0..127
    const int half = c >> 6;         // wave-uniform
    const int p    = c & 63;

    const float* wcol = W + half * (SINGLE_DIM * PAIR_DIM) + p;
    const float* srow = lds[row];

    float acc = (half == 0) ? bias[p] : 0.f;
    #pragma unroll 8
    for (int d = 0; d < SINGLE_DIM; ++d)
        acc += srow[d] * wcol[d * PAIR_DIM];

    proj[(size_t)(row0 + row) * 128 + c] = acc;

    if (rowstats) {
        float sv = acc, qv = acc * acc;
        #pragma unroll
        for (int mask = 1; mask < 64; mask <<= 1) {
            sv += __shfl_xor(sv, mask, 64);
            qv += __shfl_xor(qv, mask, 64);
        }
        if ((t & 63) == 0)
            *(float2*)(rowstats + (size_t)(row0 + row) * 4 + half * 2) =
                make_float2(sv, qv);
    }
}

// ---------------------------------------------------------------------------
// Kernel B v3: 16-lane group per (bi) x 4 j (stride 16). LN stats via
//   mean = (Si+Sj)/64,  E[x^2] = (Qi+Qj+2<pi',pj>)/64
// Only the cross-dot is per-pair: 4 FMA + a 16-lane DPP rotate-reduce
// (VALU pipe, 0 DS ops -> no lgkm stall chains; round 0 had 32 ds_swizzle
// with 4 dependent ~120cy rounds). Store layout identical to proven kernel.
// ---------------------------------------------------------------------------
__global__ __launch_bounds__(256, 6) void pair_v3_kernel(
    const float* __restrict__ proj,      // (B*N, 128)
    const float* __restrict__ rowstats,  // (B*N, 4)
    const float* __restrict__ gamma,
    const float* __restrict__ beta,
    const float* __restrict__ embed,     // (65, 64)
    float* __restrict__ out)             // (B, N, N, 64)
{
    const int t  = threadIdx.x;
    const int g  = t >> 4;
    const int p0 = (t & 15) * 4;
    const int bid = blockIdx.x;
    const int bi    = bid >> 4;
    const int jbase = (bid & 15) * 64 + g;
    const int i = bi & (N_FIXED - 1);
    const int b = bi >> 10;

    const float4 pi4 = *(const float4*)(proj + (size_t)bi * 128 + p0);
    const float4 g4  = *(const float4*)(gamma + p0);
    const float4 b4  = *(const float4*)(beta + p0);
    const float2 rsi = *(const float2*)(rowstats + (size_t)bi * 4);  // uniform

    #pragma unroll
    for (int k = 0; k < 4; ++k) {
        const int j = jbase + 16 * k;
        const size_t jrow = (size_t)b * N_FIXED + j;
        const float4 pj4 = *(const float4*)(proj + jrow * 128 + 64 + p0);
        const float2 rsj = *(const float2*)(rowstats + jrow * 4 + 2);

        float4 v;
        v.x = pi4.x + pj4.x;
        v.y = pi4.y + pj4.y;
        v.z = pi4.z + pj4.z;
        v.w = pi4.w + pj4.w;

        float dot = pi4.x * pj4.x + pi4.y * pj4.y + pi4.z * pj4.z + pi4.w * pj4.w;
        dot = rowsum16(dot);                       // <pi',pj> over 64 ch

        const float mean = (rsi.x + rsj.x) * (1.f / PAIR_DIM);
        const float ex2  = (rsi.y + rsj.y + 2.f * dot) * (1.f / PAIR_DIM);
        const float rstd = rsqrtf(ex2 - mean * mean + LN_EPS);

        const float Gx = g4.x * rstd, Gy = g4.y * rstd,
                    Gz = g4.z * rstd, Gw = g4.w * rstd;
        const float Bx = fmaf(-mean, Gx, b4.x), By = fmaf(-mean, Gy, b4.y),
                    Bz = fmaf(-mean, Gz, b4.z), Bw = fmaf(-mean, Gw, b4.w);

        int rel = j - i;
        rel = (rel < -MAX_REL) ? -MAX_REL : (rel > MAX_REL ? MAX_REL : rel);
        rel += MAX_REL;
        const float4 e4 = *(const float4*)(embed + rel * PAIR_DIM + p0);

        vfloat4 o;
        o.x = fmaxf(fmaf(v.x, Gx, Bx), 0.f) + e4.x;
        o.y = fmaxf(fmaf(v.y, Gy, By), 0.f) + e4.y;
        o.z = fmaxf(fmaf(v.z, Gz, Bz), 0.f) + e4.z;
        o.w = fmaxf(fmaf(v.w, Gw, Bw), 0.f) + e4.w;

        __builtin_nontemporal_store(o,
            (vfloat4*)(out + ((size_t)bi * N_FIXED + j) * PAIR_DIM + p0));
    }
}

// ---------------------------------------------------------------------------
// Fallback (exact round-0 kernel, proven 539 us) if workspace lacks the
// extra 32 KB for rowstats.
// ---------------------------------------------------------------------------
__global__ __launch_bounds__(256) void pair_kernel(
    const float* __restrict__ proj,
    const float* __restrict__ gamma,
    const float* __restrict__ beta,
    const float* __restrict__ embed,
    float* __restrict__ out)
{
    const int t  = threadIdx.x;
    const int g  = t >> 4;
    const int p0 = (t & 15) * 4;
    const int bid = blockIdx.x;
    const int bi    = bid >> 4;
    const int jbase = (bid & 15) * 64 + g;
    const int i = bi & (N_FIXED - 1);
    const int b = bi >> 10;

    const float4 pi4 = *(const float4*)(proj + (size_t)bi * 128 + p0);
    const float4 g4  = *(const float4*)(gamma + p0);
    const float4 b4  = *(const float4*)(beta + p0);

    float4 v[4];
    float  s[4], ss[4];
    #pragma unroll
    for (int k = 0; k < 4; ++k) {
        const int j = jbase + 16 * k;
        const float4 pj4 = *(const float4*)(proj + (size_t)(b * N_FIXED + j) * 128 + 64 + p0);
        v[k].x = pi4.x + pj4.x;
        v[k].y = pi4.y + pj4.y;
        v[k].z = pi4.z + pj4.z;
        v[k].w = pi4.w + pj4.w;
        s[k]  = v[k].x + v[k].y + v[k].z + v[k].w;
        ss[k] = v[k].x * v[k].x + v[k].y * v[k].y + v[k].z * v[k].z + v[k].w * v[k].w;
    }

    #pragma unroll
    for (int mask = 1; mask < 16; mask <<= 1) {
        #pragma unroll
        for (int k = 0; k < 4; ++k) {
            s[k]  += __shfl_xor(s[k],  mask, 64);
            ss[k] += __shfl_xor(ss[k], mask, 64);
        }
    }

    #pragma unroll
    for (int k = 0; k < 4; ++k) {
        const int j = jbase + 16 * k;
        const float mean = s[k] * (1.f / PAIR_DIM);
        const float var  = ss[k] * (1.f / PAIR_DIM) - mean * mean;
        const float rstd = rsqrtf(var + LN_EPS);

        int rel = j - i;
        rel = (rel < -MAX_REL) ? -MAX_REL : (rel > MAX_REL ? MAX_REL : rel);
        rel += MAX_REL;
        const float4 e4 = *(const float4*)(embed + rel * PAIR_DIM + p0);

        vfloat4 o;
        o.x = fmaxf((v[k].x - mean) * rstd * g4.x + b4.x, 0.f) + e4.x;
        o.y = fmaxf((v[k].y - mean) * rstd * g4.y + b4.y, 0.f) + e4.y;
        o.z = fmaxf((v[k].z - mean) * rstd * g4.z + b4.z, 0.f) + e4.z;
        o.w = fmaxf((v[k].w - mean) * rstd * g4.w + b4.w, 0.f) + e4.w;

        __builtin_nontemporal_store(o,
            (vfloat4*)(out + ((size_t)bi * N_FIXED + j) * PAIR_DIM + p0));
    }
}

extern "C" void kernel_launch(void* const* d_in, const int* in_sizes, int n_in,
                              void* d_out, int out_size, void* d_ws, size_t ws_size,
                              hipStream_t stream) {
    const float* s     = (const float*)d_in[0];   // (B, N, 256)
    const float* W     = (const float*)d_in[1];   // (512, 64)
    const float* bias  = (const float*)d_in[2];   // (64,)
    const float* gamma = (const float*)d_in[3];   // (64,)
    const float* beta  = (const float*)d_in[4];   // (64,)
    const float* embed = (const float*)d_in[5];   // (65, 64)
    float* out  = (float*)d_out;

    const int BN = in_sizes[0] / SINGLE_DIM;      // B*N = 2048

    const size_t sz_proj = (size_t)BN * 128 * sizeof(float);   // 1 MB
    const size_t sz_rs   = (size_t)BN * 4 * sizeof(float);     // 32 KB
    float* proj     = (float*)d_ws;
    float* rowstats = (float*)((char*)d_ws + sz_proj);

    const int pair_blocks = BN * (N_FIXED / 64);  // 32768

    if (ws_size >= sz_proj + sz_rs) {
        proj_kernel<<<BN / 2, 256, 0, stream>>>(s, W, bias, proj, rowstats);
        pair_v3_kernel<<<pair_blocks, 256, 0, stream>>>(proj, rowstats, gamma,
                                                        beta, embed, out);
    } else {
        proj_kernel<<<BN / 2, 256, 0, stream>>>(s, W, bias, proj, nullptr);
        pair_kernel<<<pair_blocks, 256, 0, stream>>>(proj, gamma, beta, embed, out);
    }
}